// Round 5
// baseline (115.454 us; speedup 1.0000x reference)
//
#include <hip/hip_runtime.h>

#define NB 4
#define NP 8
#define NV 2048
#define NE 2048
#define NF 4096
#define BIGV 1.0e10f
#define NCOMBO (NB * NP)       // 32
#define NSPAN 32               // edge spans (64 edges each)
#define NVG 8                  // vertex groups per block
#define VPT 16                 // vertices per thread
#define NVC 16                 // vertex chunks per combo
#define VC 128                 // vertices per chamfer block
#define NBLK (NCOMBO * NVC)    // 512 blocks: exactly 2 per CU
#define SSTRIDE 68             // span row stride (floats): 64+4 -> span bases 4 banks apart
#define PPAD 132               // part row stride (floats)

// ws: spart[512], cpart[512], volpart[512], counter[1]
//
// NOTE (round-2): cg::this_grid().sync() with 512 blocks cost ~65us on MI355X
// (device-scope barrier across 8 non-coherent XCDs). Never again.
// NOTE (round-4): v_pk_fma_f32 + min3 chain = 1.5 instr/edge-vert; VALU halved,
// LDS read pipe became critical path (96 b128/wave, broadcast still pays
// 1024B return/instr).
// NOTE (round-5): 32 spans x 8 vgroups (16 verts/thread) halves per-wave LDS
// reads (48 b128) at constant VALU -> VALU critical again (~2.6us/CU).
// Finalize fused into last block (release fence + device atomicAdd + acquire
// fence, rocPRIM-lookback pattern); 4B memset re-zeros the poisoned counter.

typedef float f32x2 __attribute__((ext_vector_type(2)));

__device__ __forceinline__ f32x2 pk_fma(f32x2 a, f32x2 b, f32x2 c) {
    f32x2 d;
    asm("v_pk_fma_f32 %0, %1, %2, %3" : "=v"(d) : "v"(a), "v"(b), "v"(c));
    return d;
}

__device__ __forceinline__ void finalize_out(
    const float* __restrict__ spart, const float* __restrict__ cpart,
    const float* __restrict__ volpart, const float* __restrict__ tv,
    float* __restrict__ out, const int tid)
{
    __shared__ float pc[NCOMBO];
    __shared__ float rv[4];
    // per-combo masked mean from 16 vchunk partials (vectorized: 4x float4 each)
    if (tid < NCOMBO) {
        const float4* s4 = (const float4*)(spart + (tid << 4));
        const float4* c4 = (const float4*)(cpart + (tid << 4));
        float S = 0.0f, C = 0.0f;
        #pragma unroll
        for (int j = 0; j < 4; j++) {
            const float4 a = s4[j], d = c4[j];
            S += (a.x + a.y) + (a.z + a.w);
            C += (d.x + d.y) + (d.z + d.w);
        }
        pc[tid] = S / fmaxf(C, 1.0f);
    }
    // volume: wave w reduces the 128 block-partials of batch b=w
    const int w = tid >> 6, lane = tid & 63;
    float vs = volpart[(w << 7) + lane] + volpart[(w << 7) + 64 + lane];
    #pragma unroll
    for (int off = 32; off > 0; off >>= 1) vs += __shfl_down(vs, off);
    if (lane == 0) rv[w] = vs;
    __syncthreads();
    if (tid < NB) {
        float a = 0.0f;
        #pragma unroll
        for (int q = 0; q < NP; q++) a += pc[tid * NP + q];
        out[tid] = a * (1.0f / NP);
        const float d = fabsf(rv[tid]) - tv[tid];
        out[4 + tid] = d * d;
    }
}

// One block = one (combo, vchunk): min over ALL 2048 edges for 128 vertices
// (32 edge-spans x 8 vertex-groups of 16) + 32 volume faces per block.
// Last-arriving block finalizes both outputs.
__global__ __launch_bounds__(256) void fused_all(
    const float* __restrict__ xs, const float* __restrict__ pm,
    const float* __restrict__ edgemaps, const int* __restrict__ elen,
    const int* __restrict__ faces, const void* __restrict__ maskp,
    const float* __restrict__ tv,
    float* __restrict__ spart, float* __restrict__ cpart,
    float* __restrict__ volpart, unsigned* __restrict__ counter,
    float* __restrict__ out)
{
    __shared__ __align__(16) float s_ex[NSPAN * SSTRIDE];  // 8.5 KB
    __shared__ __align__(16) float s_ey[NSPAN * SSTRIDE];  // 8.5 KB
    __shared__ __align__(16) float s_e2[NSPAN * SSTRIDE];  // 8.5 KB (BIG if invalid)
    __shared__ __align__(16) float part[NSPAN * PPAD];     // 16.9 KB per-span vertex mins
    __shared__ float reds[2], redc[2];
    __shared__ bool s_last;
    const int tid = threadIdx.x;
    const int bid = blockIdx.x;
    const int combo  = bid >> 4;   // b*8 + p
    const int vchunk = bid & 15;
    const int b = combo >> 3;
    const int p = combo & 7;

    // ---- stage all 2048 edges SoA: thread handles 2 edge-quads (8 edges) ----
    const int len = elen[combo];
    const float4* emapf4 = (const float4*)(edgemaps + (size_t)combo * NE * 2);
    #pragma unroll
    for (int j = 0; j < 2; j++) {
        const int q = tid + (j << 8);          // edge quad 0..511 (edges 4q..4q+3)
        const float4 f0 = emapf4[2 * q];       // ex0,ey0,ex1,ey1 (32B/lane contiguous)
        const float4 f1 = emapf4[2 * q + 1];   // ex2,ey2,ex3,ey3
        float ex[4] = { f0.x, f0.z, f1.x, f1.z };
        float ey[4] = { f0.y, f0.w, f1.y, f1.w };
        float e2[4];
        const int e0 = q << 2;
        #pragma unroll
        for (int k = 0; k < 4; k++) {
            if (e0 + k < len) {
                e2[k] = ex[k] * ex[k] + ey[k] * ey[k];
            } else {
                ex[k] = 0.0f; ey[k] = 0.0f; e2[k] = BIGV;  // ref: d2 -> BIG for invalid e
            }
        }
        const int sp = q >> 4, pr = (q & 15) << 2;   // 16 quads per 64-edge span
        *(float4*)&s_ex[sp * SSTRIDE + pr] = make_float4(ex[0], ex[1], ex[2], ex[3]);
        *(float4*)&s_ey[sp * SSTRIDE + pr] = make_float4(ey[0], ey[1], ey[2], ey[3]);
        *(float4*)&s_e2[sp * SSTRIDE + pr] = make_float4(e2[0], e2[1], e2[2], e2[3]);
    }

    // ---- project 16 owned vertices (12 coalesced dwordx4 loads) ----
    const float* M = pm + p * 12;              // uniform -> scalar loads
    const float m00 = M[0], m01 = M[1], m02 = M[2],  m03 = M[3];
    const float m10 = M[4], m11 = M[5], m12 = M[6],  m13 = M[7];
    const float m20 = M[8], m21 = M[9], m22 = M[10], m23 = M[11];

    const int vg   = tid & 7;                  // 8 vertex groups x 16 verts = 128
    const int span = tid >> 3;                 // 32 edge spans x 64 edges
    const int v0   = vchunk * VC + vg * VPT;

    float c48[48];
    {
        const float4* xv = (const float4*)(xs + ((size_t)b * NV + v0) * 3);
        #pragma unroll
        for (int j = 0; j < 12; j++) ((float4*)c48)[j] = xv[j];
    }
    f32x2 px2[VPT], py2[VPT];
    float mn[VPT];
    #pragma unroll
    for (int i = 0; i < VPT; i++) {
        const float x = c48[3 * i], y = c48[3 * i + 1], z = c48[3 * i + 2];
        const float r0 = m00 * x + m01 * y + m02 * z + m03;
        const float r1 = m10 * x + m11 * y + m12 * z + m13;
        const float r2 = m20 * x + m21 * y + m22 * z + m23;
        const float inv = 1.0f / r2;           // r2 ~ 2.0 by construction
        const float ax = -2.0f * (r0 * inv);
        const float ay = -2.0f * (r1 * inv);
        px2[i].x = ax; px2[i].y = ax;          // duplicated pair for pk_fma
        py2[i].x = ay; py2[i].y = ay;
        mn[i] = 3.0e38f;
    }

    // ---- volume gathers issued early (wave 0 lanes 0..31); drain at the barrier ----
    float fvol = 0.0f;
    if (tid < 32) {
        const int f = (bid << 5) + tid;        // global face 0..16383, contiguous per b
        const int* fc = faces + (size_t)f * 3;
        const int i0 = fc[0], i1 = fc[1], i2 = fc[2];
        const float* xb = xs + (size_t)(f >> 12) * NV * 3;
        const float ax = xb[i0 * 3], ay = xb[i0 * 3 + 1], az = xb[i0 * 3 + 2];
        const float bx = xb[i1 * 3], by = xb[i1 * 3 + 1], bz = xb[i1 * 3 + 2];
        const float cx = xb[i2 * 3], cy = xb[i2 * 3 + 1], cz = xb[i2 * 3 + 2];
        const float crx = ay * bz - az * by;
        const float cry = az * bx - ax * bz;
        const float crz = ax * by - ay * bx;
        fvol = (crx * cx + cry * cy + crz * cz) * (1.0f / 6.0f);
    }
    __syncthreads();

    // ---- hot loop: 4 edges/iter x 16 verts; 3 b128 + 64 pk_fma + 32 min3 per iter ----
    const float* bx = s_ex + span * SSTRIDE;
    const float* by = s_ey + span * SSTRIDE;
    const float* b2 = s_e2 + span * SSTRIDE;
    #pragma unroll 2
    for (int k = 0; k < 16; k++) {
        const float4 ex4 = *(const float4*)(bx + 4 * k);
        const float4 ey4 = *(const float4*)(by + 4 * k);
        const float4 e24 = *(const float4*)(b2 + 4 * k);
        f32x2 exA, exB, eyA, eyB, e2A, e2B;
        exA.x = ex4.x; exA.y = ex4.y;  exB.x = ex4.z; exB.y = ex4.w;
        eyA.x = ey4.x; eyA.y = ey4.y;  eyB.x = ey4.z; eyB.y = ey4.w;
        e2A.x = e24.x; e2A.y = e24.y;  e2B.x = e24.z; e2B.y = e24.w;
        #pragma unroll
        for (int i = 0; i < VPT; i++) {
            const f32x2 dA = pk_fma(py2[i], eyA, pk_fma(px2[i], exA, e2A));
            const f32x2 dB = pk_fma(py2[i], eyB, pk_fma(px2[i], exB, e2B));
            mn[i] = fminf(fminf(mn[i], dA.x), dA.y);   // -> v_min3_f32
            mn[i] = fminf(fminf(mn[i], dB.x), dB.y);
        }
    }

    // ---- per-span partial mins (+|pt|^2 re-added, bit-identical: pow2 scaling) ----
    {
        float val[VPT];
        #pragma unroll
        for (int i = 0; i < VPT; i++) {
            const float ax = px2[i].x, ay = py2[i].x;
            const float v2 = 0.25f * fmaf(ax, ax, ay * ay);   // == px*px+py*py exactly
            val[i] = mn[i] + v2;
        }
        float* dst = part + span * PPAD + vg * VPT;
        #pragma unroll
        for (int j = 0; j < 4; j++) *(float4*)(dst + 4 * j) = ((float4*)val)[j];
    }

    // boundary_mask dtype sniff (uniform): int32 0/1 words <=1; packed bytes exceed 1
    const unsigned* mw = (const unsigned*)maskp;
    bool as_int = true;
    #pragma unroll
    for (int k = 0; k < 16; k++)
        if (mw[k] > 1u) as_int = false;

    __syncthreads();
    float s = 0.0f, c = 0.0f;
    if (tid < VC) {
        float m = part[tid];
        #pragma unroll
        for (int sp = 1; sp < NSPAN; sp++)
            m = fminf(m, part[sp * PPAD + tid]);
        const size_t mix = (size_t)combo * NV + vchunk * VC + tid;
        const float msk = as_int ? (((const int*)maskp)[mix] ? 1.0f : 0.0f)
                                 : (((const unsigned char*)maskp)[mix] ? 1.0f : 0.0f);
        s = m * msk;
        c = msk;
    }
    #pragma unroll
    for (int off = 32; off > 0; off >>= 1) {
        s += __shfl_down(s, off);
        c += __shfl_down(c, off);
    }
    if (tid < VC && (tid & 63) == 0) { reds[tid >> 6] = s; redc[tid >> 6] = c; }

    // volume wave-reduce (lanes 32..63 contribute 0; all lanes active here)
    #pragma unroll
    for (int off = 32; off > 0; off >>= 1) fvol += __shfl_down(fvol, off);

    __syncthreads();
    if (tid == 0) {
        spart[bid]   = reds[0] + reds[1];
        cpart[bid]   = redc[0] + redc[1];
        volpart[bid] = fvol;
    }

    // ---- last-block finalize: release fence -> device atomic -> acquire fence ----
    __threadfence();                           // tid0's partial stores visible device-wide
    if (tid == 0) {
        const unsigned old = atomicAdd(counter, 1u);
        s_last = (old == NBLK - 1);
    }
    __syncthreads();
    if (s_last) {
        __threadfence();                       // acquire: see all blocks' partials
        finalize_out(spart, cpart, volpart, tv, out, tid);
    }
}

extern "C" void kernel_launch(void* const* d_in, const int* in_sizes, int n_in,
                              void* d_out, int out_size, void* d_ws, size_t ws_size,
                              hipStream_t stream)
{
    const float* xs       = (const float*)d_in[0];
    const float* pm       = (const float*)d_in[1];
    const float* edgemaps = (const float*)d_in[2];
    const int*   elen     = (const int*)d_in[3];
    const void*  mask     = d_in[4];
    const int*   faces    = (const int*)d_in[5];
    const float* tv       = (const float*)d_in[6];
    float* out = (float*)d_out;

    float*    spart   = (float*)d_ws;           // 512 floats
    float*    cpart   = spart + NBLK;           // 512 floats
    float*    volpart = cpart + NBLK;           // 512 floats
    unsigned* counter = (unsigned*)(volpart + NBLK);

    hipMemsetAsync(counter, 0, sizeof(unsigned), stream);   // ws is re-poisoned each iter
    fused_all<<<dim3(NBLK), dim3(256), 0, stream>>>(
        xs, pm, edgemaps, elen, faces, mask, tv, spart, cpart, volpart, counter, out);
}

// Round 6
// 78.482 us; speedup vs baseline: 1.4711x; 1.4711x over previous
//
#include <hip/hip_runtime.h>

#define NB 4
#define NP 8
#define NV 2048
#define NE 2048
#define NF 4096
#define BIGV 1.0e10f
#define NCOMBO (NB * NP)       // 32
#define NSPAN 32               // edge spans (64 edges each)
#define NVG 8                  // vertex groups per block
#define VPT 16                 // vertices per thread
#define NVC 16                 // vertex chunks per combo
#define VC 128                 // vertices per chamfer block
#define NBLK (NCOMBO * NVC)    // 512 blocks: exactly 2 per CU
#define SSTRIDE 68             // span row stride (floats): 64+4 -> span bases 4 banks apart
#define PPAD 132               // part row stride (floats)

// ws: spart[512], cpart[512], volpart[512]
//
// HARD RULES from this session's measurements (MI355X, 512-block grid):
//  * r2: cg::this_grid().sync() = ~65us (device-scope barrier across 8
//    non-coherent XCDs).
//  * r5: __threadfence() + device atomicAdd last-block pattern = ~60us (same
//    L2 writeback/invalidate storm; L2-resident replays still 63us).
//  => NO device-scope fences/atomics. Plain 2-dispatch: big kernel emits
//     per-block partials, 1-block finalize kernel reduces them (~3us).
// NOTE (r4): v_pk_fma_f32 + min3 chain = 1.5 instr/edge-vert (VALU halved vs
// scalar). NOTE (r5 keep): 32 spans x 8 vgroups (16 verts/thread) halves
// per-wave LDS b128 reads at constant VALU.

typedef float f32x2 __attribute__((ext_vector_type(2)));

__device__ __forceinline__ f32x2 pk_fma(f32x2 a, f32x2 b, f32x2 c) {
    f32x2 d;
    asm("v_pk_fma_f32 %0, %1, %2, %3" : "=v"(d) : "v"(a), "v"(b), "v"(c));
    return d;
}

// K1: one block = one (combo, vchunk): min over ALL 2048 edges for 128
// vertices (32 edge-spans x 8 vertex-groups of 16) + 32 volume faces per
// block. Emits per-block masked-sum/count/volume partials only.
__global__ __launch_bounds__(256) void fused_all(
    const float* __restrict__ xs, const float* __restrict__ pm,
    const float* __restrict__ edgemaps, const int* __restrict__ elen,
    const int* __restrict__ faces, const void* __restrict__ maskp,
    float* __restrict__ spart, float* __restrict__ cpart,
    float* __restrict__ volpart)
{
    __shared__ __align__(16) float s_ex[NSPAN * SSTRIDE];  // 8.5 KB
    __shared__ __align__(16) float s_ey[NSPAN * SSTRIDE];  // 8.5 KB
    __shared__ __align__(16) float s_e2[NSPAN * SSTRIDE];  // 8.5 KB (BIG if invalid)
    __shared__ __align__(16) float part[NSPAN * PPAD];     // 16.9 KB per-span vertex mins
    __shared__ float reds[2], redc[2];
    const int tid = threadIdx.x;
    const int bid = blockIdx.x;
    const int combo  = bid >> 4;   // b*8 + p
    const int vchunk = bid & 15;
    const int b = combo >> 3;
    const int p = combo & 7;

    // ---- stage all 2048 edges SoA: thread handles 2 edge-quads (8 edges) ----
    const int len = elen[combo];
    const float4* emapf4 = (const float4*)(edgemaps + (size_t)combo * NE * 2);
    #pragma unroll
    for (int j = 0; j < 2; j++) {
        const int q = tid + (j << 8);          // edge quad 0..511 (edges 4q..4q+3)
        const float4 f0 = emapf4[2 * q];       // ex0,ey0,ex1,ey1 (32B/lane contiguous)
        const float4 f1 = emapf4[2 * q + 1];   // ex2,ey2,ex3,ey3
        float ex[4] = { f0.x, f0.z, f1.x, f1.z };
        float ey[4] = { f0.y, f0.w, f1.y, f1.w };
        float e2[4];
        const int e0 = q << 2;
        #pragma unroll
        for (int k = 0; k < 4; k++) {
            if (e0 + k < len) {
                e2[k] = ex[k] * ex[k] + ey[k] * ey[k];
            } else {
                ex[k] = 0.0f; ey[k] = 0.0f; e2[k] = BIGV;  // ref: d2 -> BIG for invalid e
            }
        }
        const int sp = q >> 4, pr = (q & 15) << 2;   // 16 quads per 64-edge span
        *(float4*)&s_ex[sp * SSTRIDE + pr] = make_float4(ex[0], ex[1], ex[2], ex[3]);
        *(float4*)&s_ey[sp * SSTRIDE + pr] = make_float4(ey[0], ey[1], ey[2], ey[3]);
        *(float4*)&s_e2[sp * SSTRIDE + pr] = make_float4(e2[0], e2[1], e2[2], e2[3]);
    }

    // ---- project 16 owned vertices (12 coalesced dwordx4 loads) ----
    const float* M = pm + p * 12;              // uniform -> scalar loads
    const float m00 = M[0], m01 = M[1], m02 = M[2],  m03 = M[3];
    const float m10 = M[4], m11 = M[5], m12 = M[6],  m13 = M[7];
    const float m20 = M[8], m21 = M[9], m22 = M[10], m23 = M[11];

    const int vg   = tid & 7;                  // 8 vertex groups x 16 verts = 128
    const int span = tid >> 3;                 // 32 edge spans x 64 edges
    const int v0   = vchunk * VC + vg * VPT;

    float c48[48];
    {
        const float4* xv = (const float4*)(xs + ((size_t)b * NV + v0) * 3);
        #pragma unroll
        for (int j = 0; j < 12; j++) ((float4*)c48)[j] = xv[j];
    }
    f32x2 px2[VPT], py2[VPT];
    float mn[VPT];
    #pragma unroll
    for (int i = 0; i < VPT; i++) {
        const float x = c48[3 * i], y = c48[3 * i + 1], z = c48[3 * i + 2];
        const float r0 = m00 * x + m01 * y + m02 * z + m03;
        const float r1 = m10 * x + m11 * y + m12 * z + m13;
        const float r2 = m20 * x + m21 * y + m22 * z + m23;
        const float inv = 1.0f / r2;           // r2 ~ 2.0 by construction
        const float ax = -2.0f * (r0 * inv);
        const float ay = -2.0f * (r1 * inv);
        px2[i].x = ax; px2[i].y = ax;          // duplicated pair for pk_fma
        py2[i].x = ay; py2[i].y = ay;
        mn[i] = 3.0e38f;
    }

    // ---- volume gathers issued early (wave 0 lanes 0..31); drain at the barrier ----
    float fvol = 0.0f;
    if (tid < 32) {
        const int f = (bid << 5) + tid;        // global face 0..16383, contiguous per b
        const int* fc = faces + (size_t)f * 3;
        const int i0 = fc[0], i1 = fc[1], i2 = fc[2];
        const float* xb = xs + (size_t)(f >> 12) * NV * 3;
        const float ax = xb[i0 * 3], ay = xb[i0 * 3 + 1], az = xb[i0 * 3 + 2];
        const float bx = xb[i1 * 3], by = xb[i1 * 3 + 1], bz = xb[i1 * 3 + 2];
        const float cx = xb[i2 * 3], cy = xb[i2 * 3 + 1], cz = xb[i2 * 3 + 2];
        const float crx = ay * bz - az * by;
        const float cry = az * bx - ax * bz;
        const float crz = ax * by - ay * bx;
        fvol = (crx * cx + cry * cy + crz * cz) * (1.0f / 6.0f);
    }
    __syncthreads();

    // ---- hot loop: 4 edges/iter x 16 verts; 3 b128 + 64 pk_fma + 32 min3 per iter ----
    const float* bx = s_ex + span * SSTRIDE;
    const float* by = s_ey + span * SSTRIDE;
    const float* b2 = s_e2 + span * SSTRIDE;
    #pragma unroll 2
    for (int k = 0; k < 16; k++) {
        const float4 ex4 = *(const float4*)(bx + 4 * k);
        const float4 ey4 = *(const float4*)(by + 4 * k);
        const float4 e24 = *(const float4*)(b2 + 4 * k);
        f32x2 exA, exB, eyA, eyB, e2A, e2B;
        exA.x = ex4.x; exA.y = ex4.y;  exB.x = ex4.z; exB.y = ex4.w;
        eyA.x = ey4.x; eyA.y = ey4.y;  eyB.x = ey4.z; eyB.y = ey4.w;
        e2A.x = e24.x; e2A.y = e24.y;  e2B.x = e24.z; e2B.y = e24.w;
        #pragma unroll
        for (int i = 0; i < VPT; i++) {
            const f32x2 dA = pk_fma(py2[i], eyA, pk_fma(px2[i], exA, e2A));
            const f32x2 dB = pk_fma(py2[i], eyB, pk_fma(px2[i], exB, e2B));
            mn[i] = fminf(fminf(mn[i], dA.x), dA.y);   // -> v_min3_f32
            mn[i] = fminf(fminf(mn[i], dB.x), dB.y);
        }
    }

    // ---- per-span partial mins (+|pt|^2 re-added, bit-identical: pow2 scaling) ----
    {
        float val[VPT];
        #pragma unroll
        for (int i = 0; i < VPT; i++) {
            const float ax = px2[i].x, ay = py2[i].x;
            const float v2 = 0.25f * fmaf(ax, ax, ay * ay);   // == px*px+py*py exactly
            val[i] = mn[i] + v2;
        }
        float* dst = part + span * PPAD + vg * VPT;
        #pragma unroll
        for (int j = 0; j < 4; j++) *(float4*)(dst + 4 * j) = ((float4*)val)[j];
    }

    // boundary_mask dtype sniff (uniform): int32 0/1 words <=1; packed bytes exceed 1
    const unsigned* mw = (const unsigned*)maskp;
    bool as_int = true;
    #pragma unroll
    for (int k = 0; k < 16; k++)
        if (mw[k] > 1u) as_int = false;

    __syncthreads();
    float s = 0.0f, c = 0.0f;
    if (tid < VC) {
        float m = part[tid];
        #pragma unroll
        for (int sp = 1; sp < NSPAN; sp++)
            m = fminf(m, part[sp * PPAD + tid]);
        const size_t mix = (size_t)combo * NV + vchunk * VC + tid;
        const float msk = as_int ? (((const int*)maskp)[mix] ? 1.0f : 0.0f)
                                 : (((const unsigned char*)maskp)[mix] ? 1.0f : 0.0f);
        s = m * msk;
        c = msk;
    }
    #pragma unroll
    for (int off = 32; off > 0; off >>= 1) {
        s += __shfl_down(s, off);
        c += __shfl_down(c, off);
    }
    if (tid < VC && (tid & 63) == 0) { reds[tid >> 6] = s; redc[tid >> 6] = c; }

    // volume wave-reduce (lanes 32..63 contribute 0; all lanes active here)
    #pragma unroll
    for (int off = 32; off > 0; off >>= 1) fvol += __shfl_down(fvol, off);

    __syncthreads();
    if (tid == 0) {
        spart[bid]   = reds[0] + reds[1];
        cpart[bid]   = redc[0] + redc[1];
        volpart[bid] = fvol;
    }
}

// K2: finalize both outputs (1 small block, ~3us incl. launch -- cheaper than
// any device-scope sync by 20x on this chip).
__global__ __launch_bounds__(256) void finalize_k(
    const float* __restrict__ spart, const float* __restrict__ cpart,
    const float* __restrict__ volpart, const float* __restrict__ tv,
    float* __restrict__ out)
{
    __shared__ float pc[NCOMBO];
    __shared__ float rv[4];
    const int tid = threadIdx.x;
    // per-combo masked mean from 16 vchunk partials (vectorized: 4x float4 each)
    if (tid < NCOMBO) {
        const float4* s4 = (const float4*)(spart + (tid << 4));
        const float4* c4 = (const float4*)(cpart + (tid << 4));
        float S = 0.0f, C = 0.0f;
        #pragma unroll
        for (int j = 0; j < 4; j++) {
            const float4 a = s4[j], d = c4[j];
            S += (a.x + a.y) + (a.z + a.w);
            C += (d.x + d.y) + (d.z + d.w);
        }
        pc[tid] = S / fmaxf(C, 1.0f);
    }
    // volume: wave w reduces the 128 block-partials of batch b=w
    const int w = tid >> 6, lane = tid & 63;
    float vs = volpart[(w << 7) + lane] + volpart[(w << 7) + 64 + lane];
    #pragma unroll
    for (int off = 32; off > 0; off >>= 1) vs += __shfl_down(vs, off);
    if (lane == 0) rv[w] = vs;
    __syncthreads();
    if (tid < NB) {
        float a = 0.0f;
        #pragma unroll
        for (int q = 0; q < NP; q++) a += pc[tid * NP + q];
        out[tid] = a * (1.0f / NP);
        const float d = fabsf(rv[tid]) - tv[tid];
        out[4 + tid] = d * d;
    }
}

extern "C" void kernel_launch(void* const* d_in, const int* in_sizes, int n_in,
                              void* d_out, int out_size, void* d_ws, size_t ws_size,
                              hipStream_t stream)
{
    const float* xs       = (const float*)d_in[0];
    const float* pm       = (const float*)d_in[1];
    const float* edgemaps = (const float*)d_in[2];
    const int*   elen     = (const int*)d_in[3];
    const void*  mask     = d_in[4];
    const int*   faces    = (const int*)d_in[5];
    const float* tv       = (const float*)d_in[6];
    float* out = (float*)d_out;

    float* spart   = (float*)d_ws;              // 512 floats
    float* cpart   = spart + NBLK;              // 512 floats
    float* volpart = cpart + NBLK;              // 512 floats

    fused_all<<<dim3(NBLK), dim3(256), 0, stream>>>(
        xs, pm, edgemaps, elen, faces, mask, spart, cpart, volpart);
    finalize_k<<<dim3(1), dim3(256), 0, stream>>>(spart, cpart, volpart, tv, out);
}